// Round 1
// baseline (3015.408 us; speedup 1.0000x reference)
//
#include <hip/hip_runtime.h>
#include <hip/hip_bf16.h>
#include <math.h>

#define BT   16384   // B*T
#define HIDS 256
#define NHS  8
#define DHS  32
#define NVS  20
#define FFS  1024

__device__ __forceinline__ float bf2f(unsigned int u16) {
    union { unsigned int u; float f; } cv; cv.u = u16 << 16; return cv.f;
}
__device__ __forceinline__ unsigned short f2bf(float f) {
    __hip_bfloat16 h = __float2bfloat16(f);
    union { __hip_bfloat16 h; unsigned short u; } cv; cv.h = h; return cv.u;
}

// ---------------- K0: fold query into key projection ----------------
// q[j] = cls@wq + bq ; qk[c][h] = sum_d wk[c][h*32+d]*q[h*32+d] ; qb[h] = bk[h]·q[h]
__global__ __launch_bounds__(256) void k_fold(
        const float* __restrict__ cls, const float* __restrict__ wq,
        const float* __restrict__ bq, const float* __restrict__ wk,
        const float* __restrict__ bk, float* __restrict__ qk,
        float* __restrict__ qb) {
    __shared__ float s_q[HIDS];
    int tid = threadIdx.x;
    float acc = bq[tid];
    for (int c = 0; c < HIDS; ++c) acc += cls[c] * wq[c * HIDS + tid];
    s_q[tid] = acc;
    __syncthreads();
    int c = tid;
    #pragma unroll
    for (int h = 0; h < NHS; ++h) {
        float a = 0.f;
        #pragma unroll
        for (int d = 0; d < DHS; ++d) a += wk[c * HIDS + h * DHS + d] * s_q[h * DHS + d];
        qk[c * NHS + h] = a;
    }
    if (tid < NHS) {
        float a = 0.f;
        #pragma unroll
        for (int d = 0; d < DHS; ++d) a += bk[tid * DHS + d] * s_q[tid * DHS + d];
        qb[tid] = a;
    }
}

// ---------------- K1: per-token attention -> xmix (bf16) ----------------
__global__ __launch_bounds__(256) void k_attn(
        const float* __restrict__ x, const float* __restrict__ qk,
        const float* __restrict__ qb, unsigned short* __restrict__ xmix) {
    __shared__ float s_x[NVS][HIDS + 1];
    __shared__ float s_qk[HIDS * NHS];
    __shared__ float s_qb[NHS];
    __shared__ float s_sc[NHS * NVS];
    __shared__ float s_at[NHS * NVS];
    int tid = threadIdx.x;
    int t = blockIdx.x;
    const float4* xr = (const float4*)(x + (size_t)t * (NVS * HIDS));
    #pragma unroll
    for (int k = 0; k < 5; ++k) {
        float4 f = xr[k * 256 + tid];
        int flat = (k * 256 + tid) * 4;
        int v = flat >> 8, c = flat & 255;
        s_x[v][c] = f.x; s_x[v][c + 1] = f.y; s_x[v][c + 2] = f.z; s_x[v][c + 3] = f.w;
    }
    #pragma unroll
    for (int k = 0; k < 8; ++k) s_qk[k * 256 + tid] = qk[k * 256 + tid];
    if (tid < NHS) s_qb[tid] = qb[tid];
    __syncthreads();
    if (tid < NVS * NHS) {
        int v = tid >> 3, h = tid & 7;
        float a = s_qb[h];
        #pragma unroll 4
        for (int c = 0; c < HIDS; ++c) a += s_x[v][c] * s_qk[c * NHS + h];
        s_sc[h * NVS + v] = a * 0.17677669529663687f;  // 1/sqrt(32)
    }
    __syncthreads();
    if (tid < NHS) {
        float m = -1e30f;
        #pragma unroll
        for (int v = 0; v < NVS; ++v) m = fmaxf(m, s_sc[tid * NVS + v]);
        float sum = 0.f;
        #pragma unroll
        for (int v = 0; v < NVS; ++v) {
            float e = expf(s_sc[tid * NVS + v] - m);
            s_at[tid * NVS + v] = e; sum += e;
        }
        float inv = 1.f / sum;
        #pragma unroll
        for (int v = 0; v < NVS; ++v) s_at[tid * NVS + v] *= inv;
    }
    __syncthreads();
    int c = tid;
    unsigned short* outp = xmix + (size_t)t * (NHS * HIDS);
    #pragma unroll
    for (int h = 0; h < NHS; ++h) {
        float a = 0.f;
        #pragma unroll
        for (int v = 0; v < NVS; ++v) a += s_at[h * NVS + v] * s_x[v][c];
        outp[h * HIDS + c] = f2bf(a);
    }
}

// ---------------- K2: block-diagonal V projection: ctx = xmix @ wv(head) + bv ----
__global__ __launch_bounds__(256) void k_vproj(
        const unsigned short* __restrict__ xmix, const float* __restrict__ wv,
        const float* __restrict__ bv, float* __restrict__ outp) {
    __shared__ float s_xm[16][HIDS + 1];
    int tid = threadIdx.x;
    int t0 = blockIdx.x * 16;
    int r = tid >> 4, jg = tid & 15;
    for (int h = 0; h < NHS; ++h) {
        __syncthreads();
        #pragma unroll
        for (int i = 0; i < 16; ++i) {
            int idx = i * 256 + tid;
            int rr = idx >> 8, c = idx & 255;
            s_xm[rr][c] = bf2f(xmix[(size_t)(t0 + rr) * (NHS * HIDS) + h * HIDS + c]);
        }
        __syncthreads();
        int o = h * DHS + jg * 2;
        float a0 = 0.f, a1 = 0.f;
        #pragma unroll 4
        for (int c = 0; c < HIDS; ++c) {
            float a = s_xm[r][c];
            const float2 w = *(const float2*)(wv + c * HIDS + o);
            a0 += a * w.x; a1 += a * w.y;
        }
        float2 res; res.x = a0 + bv[o]; res.y = a1 + bv[o + 1];
        *(float2*)(outp + (size_t)(t0 + r) * HIDS + o) = res;
    }
}

// ---------------- generic token-tiled GEMM: out = act(A @ W + bias) -------------
// 16 rows/block, 256 cols per y-tile; thread (r=tid/16, jg=tid%16) does 16 cols.
template <int K, int N, bool IN_BF16, bool OUT_BF16, bool DO_GELU>
__global__ __launch_bounds__(256) void k_gemm(
        const void* __restrict__ Ain, const float* __restrict__ W,
        const float* __restrict__ bias, void* __restrict__ outp) {
    constexpr int PAD = (16 * (K + 1) * 4 <= 65536) ? 1 : 0;
    __shared__ float s_a[16 * (K + PAD)];
    int tid = threadIdx.x;
    int t0 = blockIdx.x * 16;
    int ybase = blockIdx.y * 256;
    if (IN_BF16) {
        const unsigned int* A2 = (const unsigned int*)Ain + (((size_t)t0 * K) >> 1);
        #pragma unroll
        for (int i = 0; i < 16 * K / 512; ++i) {
            int idx2 = i * 256 + tid;
            unsigned int u = A2[idx2];
            int flat = idx2 * 2;
            int r = flat / K, c = flat % K;
            s_a[r * (K + PAD) + c] = bf2f(u & 0xffffu);
            s_a[r * (K + PAD) + c + 1] = bf2f(u >> 16);
        }
    } else {
        const float4* A4 = (const float4*)((const float*)Ain + (size_t)t0 * K);
        #pragma unroll
        for (int i = 0; i < 16 * K / 1024; ++i) {
            int idx4 = i * 256 + tid;
            float4 f = A4[idx4];
            int flat = idx4 * 4;
            int r = flat / K, c = flat % K;
            float* p = &s_a[r * (K + PAD) + c];
            p[0] = f.x; p[1] = f.y; p[2] = f.z; p[3] = f.w;
        }
    }
    __syncthreads();
    int r = tid >> 4, jg = tid & 15;
    int o0 = ybase + jg * 16;
    float acc[16];
    #pragma unroll
    for (int k = 0; k < 16; ++k) acc[k] = 0.f;
    const float* arow = &s_a[r * (K + PAD)];
    #pragma unroll 4
    for (int c = 0; c < K; ++c) {
        float a = arow[c];
        const float4* wr = (const float4*)(W + (size_t)c * N + o0);
        float4 w0 = wr[0], w1 = wr[1], w2 = wr[2], w3 = wr[3];
        acc[0] += a * w0.x; acc[1] += a * w0.y; acc[2] += a * w0.z; acc[3] += a * w0.w;
        acc[4] += a * w1.x; acc[5] += a * w1.y; acc[6] += a * w1.z; acc[7] += a * w1.w;
        acc[8] += a * w2.x; acc[9] += a * w2.y; acc[10] += a * w2.z; acc[11] += a * w2.w;
        acc[12] += a * w3.x; acc[13] += a * w3.y; acc[14] += a * w3.z; acc[15] += a * w3.w;
    }
    float res[16];
    #pragma unroll
    for (int k = 0; k < 16; ++k) {
        float v = acc[k] + bias[o0 + k];
        if (DO_GELU) v = 0.5f * v * (1.f + erff(v * 0.70710678118654752f));
        res[k] = v;
    }
    if (OUT_BF16) {
        unsigned int* o2 = (unsigned int*)outp + ((((size_t)(t0 + r)) * N + o0) >> 1);
        #pragma unroll
        for (int k = 0; k < 8; ++k)
            o2[k] = (unsigned int)f2bf(res[2 * k]) | ((unsigned int)f2bf(res[2 * k + 1]) << 16);
    } else {
        float* of = (float*)outp + (size_t)(t0 + r) * N + o0;
        #pragma unroll
        for (int k = 0; k < 4; ++k) {
            float4 f; f.x = res[4 * k]; f.y = res[4 * k + 1];
            f.z = res[4 * k + 2]; f.w = res[4 * k + 3];
            ((float4*)of)[k] = f;
        }
    }
}

// ---------------- LayerNorm: one wave per token -------------------------------
__global__ __launch_bounds__(256) void k_ln(
        const float* __restrict__ in, const float* __restrict__ g,
        const float* __restrict__ b, float* __restrict__ outp) {
    int tid = threadIdx.x;
    int t = blockIdx.x * 4 + (tid >> 6);
    int l = tid & 63;
    float4 v = ((const float4*)(in + (size_t)t * HIDS))[l];
    float s = v.x + v.y + v.z + v.w;
    float sq = v.x * v.x + v.y * v.y + v.z * v.z + v.w * v.w;
    #pragma unroll
    for (int m = 1; m < 64; m <<= 1) {
        s += __shfl_xor(s, m, 64);
        sq += __shfl_xor(sq, m, 64);
    }
    float mean = s * (1.f / HIDS);
    float var = sq * (1.f / HIDS) - mean * mean;
    float rstd = rsqrtf(var + 1e-5f);
    float4 g4 = ((const float4*)g)[l];
    float4 b4 = ((const float4*)b)[l];
    float4 o;
    o.x = (v.x - mean) * rstd * g4.x + b4.x;
    o.y = (v.y - mean) * rstd * g4.y + b4.y;
    o.z = (v.z - mean) * rstd * g4.z + b4.z;
    o.w = (v.w - mean) * rstd * g4.w + b4.w;
    ((float4*)(outp + (size_t)t * HIDS))[l] = o;
}

// ---------------- K8: selection logits + softmax -> weights -------------------
__global__ __launch_bounds__(256) void k_wsoft(
        const float* __restrict__ in, const float* __restrict__ ww,
        const float* __restrict__ bw, float* __restrict__ wout) {
    __shared__ float s_p[16][HIDS + 1];
    __shared__ float s_lg[16][NVS];
    int tid = threadIdx.x;
    int t0 = blockIdx.x * 16;
    #pragma unroll
    for (int i = 0; i < 4; ++i) {
        int idx4 = i * 256 + tid;
        float4 f = ((const float4*)(in + (size_t)t0 * HIDS))[idx4];
        int flat = idx4 * 4;
        int r = flat >> 8, c = flat & 255;
        s_p[r][c] = f.x; s_p[r][c + 1] = f.y; s_p[r][c + 2] = f.z; s_p[r][c + 3] = f.w;
    }
    __syncthreads();
    int r = tid >> 4, jg = tid & 15;
    if (jg < 10) {
        int o = jg * 2;
        float a0 = bw[o], a1 = bw[o + 1];
        #pragma unroll 4
        for (int c = 0; c < HIDS; ++c) {
            float a = s_p[r][c];
            const float2 w = *(const float2*)(ww + c * NVS + o);
            a0 += a * w.x; a1 += a * w.y;
        }
        s_lg[r][o] = a0; s_lg[r][o + 1] = a1;
    }
    __syncthreads();
    if (tid < 16) {
        int rr = tid;
        float m = -1e30f;
        #pragma unroll
        for (int v = 0; v < NVS; ++v) m = fmaxf(m, s_lg[rr][v]);
        float e[NVS];
        float sum = 0.f;
        #pragma unroll
        for (int v = 0; v < NVS; ++v) { e[v] = expf(s_lg[rr][v] - m); sum += e[v]; }
        float inv = 1.f / sum;
        #pragma unroll
        for (int v = 0; v < NVS; ++v) wout[(size_t)(t0 + rr) * NVS + v] = e[v] * inv;
    }
}

// ---------------- K9: vs_output = weights . x ---------------------------------
__global__ __launch_bounds__(256) void k_vsout(
        const float* __restrict__ x, const float* __restrict__ wts,
        float* __restrict__ outp) {
    int tid = threadIdx.x;
    int t = blockIdx.x * 4 + (tid >> 6);
    int l = tid & 63;
    const float4* xt = (const float4*)(x + (size_t)t * (NVS * HIDS));
    const float* wr = wts + (size_t)t * NVS;
    float4 acc = make_float4(0.f, 0.f, 0.f, 0.f);
    #pragma unroll
    for (int v = 0; v < NVS; ++v) {
        float w = wr[v];
        float4 a = xt[v * 64 + l];
        acc.x += w * a.x; acc.y += w * a.y; acc.z += w * a.z; acc.w += w * a.w;
    }
    ((float4*)(outp + (size_t)t * HIDS))[l] = acc;
}

extern "C" void kernel_launch(void* const* d_in, const int* in_sizes, int n_in,
                              void* d_out, int out_size, void* d_ws, size_t ws_size,
                              hipStream_t stream) {
    const float* x     = (const float*)d_in[0];
    const float* cls   = (const float*)d_in[1];
    const float* wq    = (const float*)d_in[2];
    const float* bq    = (const float*)d_in[3];
    const float* wk    = (const float*)d_in[4];
    const float* bk    = (const float*)d_in[5];
    const float* wv    = (const float*)d_in[6];
    const float* bv    = (const float*)d_in[7];
    const float* wo    = (const float*)d_in[8];
    const float* bo    = (const float*)d_in[9];
    const float* ln1_g = (const float*)d_in[10];
    const float* ln1_b = (const float*)d_in[11];
    const float* w1    = (const float*)d_in[12];
    const float* b1    = (const float*)d_in[13];
    const float* w2    = (const float*)d_in[14];
    const float* b2    = (const float*)d_in[15];
    const float* ln2_g = (const float*)d_in[16];
    const float* ln2_b = (const float*)d_in[17];
    const float* ww    = (const float*)d_in[18];
    const float* bw    = (const float*)d_in[19];

    float* outf  = (float*)d_out;
    float* vs_out = outf;                         // [BT, 256]
    float* w_out  = outf + (size_t)BT * HIDS;     // [BT, 20]

    char* ws = (char*)d_ws;
    float* qk = (float*)ws;                       // 2048 floats
    float* qb = qk + 2048;                        // 8 floats
    unsigned short* bufA = (unsigned short*)(ws + 9216);              // BT*2048 bf16 (xmix, later h2)
    float* buf0 = (float*)(ws + 9216 + (size_t)BT * 2048 * 2);        // BT*256 f32
    float* buf1 = buf0 + (size_t)BT * HIDS;                           // BT*256 f32

    k_fold<<<1, 256, 0, stream>>>(cls, wq, bq, wk, bk, qk, qb);
    k_attn<<<BT, 256, 0, stream>>>(x, qk, qb, bufA);
    k_vproj<<<BT / 16, 256, 0, stream>>>(bufA, wv, bv, buf0);
    k_gemm<256, 256, false, false, false><<<dim3(BT / 16, 1), 256, 0, stream>>>(buf0, wo, bo, buf1);
    k_ln<<<BT / 4, 256, 0, stream>>>(buf1, ln1_g, ln1_b, buf0);
    k_gemm<256, 1024, false, true, true><<<dim3(BT / 16, 4), 256, 0, stream>>>(buf0, w1, b1, bufA);
    k_gemm<1024, 256, true, false, false><<<dim3(BT / 16, 1), 256, 0, stream>>>(bufA, w2, b2, buf1);
    k_ln<<<BT / 4, 256, 0, stream>>>(buf1, ln2_g, ln2_b, buf0);
    k_wsoft<<<BT / 16, 256, 0, stream>>>(buf0, ww, bw, w_out);
    k_vsout<<<BT / 4, 256, 0, stream>>>(x, w_out, vs_out);
}

// Round 2
// 742.222 us; speedup vs baseline: 4.0627x; 4.0627x over previous
//
#include <hip/hip_runtime.h>
#include <hip/hip_bf16.h>
#include <math.h>

#define BT   16384
#define HIDS 256
#define NHS  8
#define NVS  20

typedef __attribute__((ext_vector_type(8))) short short8;
typedef __attribute__((ext_vector_type(4))) float floatx4;

__device__ __forceinline__ float bf2f(unsigned int u) {
    union { unsigned int u; float f; } cv; cv.u = u << 16; return cv.f;
}
__device__ __forceinline__ unsigned short f2bf(float f) {
    union { __hip_bfloat16 h; unsigned short u; } cv; cv.h = __float2bfloat16(f); return cv.u;
}
__device__ __forceinline__ unsigned int pk2(float a, float b) {
    return (unsigned int)f2bf(a) | ((unsigned int)f2bf(b) << 16);
}
__device__ __forceinline__ void gload16(const void* g, void* l) {
    __builtin_amdgcn_global_load_lds(
        (const __attribute__((address_space(1))) unsigned int*)g,
        (__attribute__((address_space(3))) unsigned int*)l, 16, 0, 0);
}

// ---------- prep: fold query into key proj -> qkbT [16][256] bf16, qb[8] ----------
__global__ __launch_bounds__(256) void k_fold(
        const float* __restrict__ cls, const float* __restrict__ wq,
        const float* __restrict__ bq, const float* __restrict__ wk,
        const float* __restrict__ bk, unsigned short* __restrict__ qkbT,
        float* __restrict__ qb) {
    __shared__ float s_q[HIDS];
    int tid = threadIdx.x;
    float acc = bq[tid];
    for (int c = 0; c < HIDS; ++c) acc += cls[c] * wq[c * HIDS + tid];
    s_q[tid] = acc;
    __syncthreads();
    int c = tid;
    #pragma unroll
    for (int h = 0; h < NHS; ++h) {
        float a = 0.f;
        #pragma unroll
        for (int d = 0; d < 32; ++d) a += wk[c * HIDS + h * 32 + d] * s_q[h * 32 + d];
        qkbT[h * HIDS + c] = f2bf(a);
    }
    #pragma unroll
    for (int h = NHS; h < 16; ++h) qkbT[h * HIDS + c] = 0;
    if (tid < NHS) {
        float a = 0.f;
        #pragma unroll
        for (int d = 0; d < 32; ++d) a += bk[tid * 32 + d] * s_q[tid * 32 + d];
        qb[tid] = a;
    }
}

// ---------- prep: bvo = bv@wo + bo ----------
__global__ __launch_bounds__(256) void k_bvo(
        const float* __restrict__ bv, const float* __restrict__ wo,
        const float* __restrict__ bo, float* __restrict__ bvo) {
    int j = threadIdx.x;
    float a = bo[j];
    for (int i = 0; i < HIDS; ++i) a += bv[i] * wo[i * HIDS + j];
    bvo[j] = a;
}

// ---------- prep: wvo_t[j][h*256+c] = sum_d wv[c][h*32+d]*wo[h*32+d][j] (bf16) ----
__global__ __launch_bounds__(256) void k_wvo(
        const float* __restrict__ wv, const float* __restrict__ wo,
        unsigned short* __restrict__ wvo_t) {
    int hc = blockIdx.x; int h = hc >> 8, c = hc & 255;
    __shared__ float s_wv[32];
    int tid = threadIdx.x;
    if (tid < 32) s_wv[tid] = wv[c * HIDS + h * 32 + tid];
    __syncthreads();
    float a = 0.f;
    #pragma unroll 8
    for (int d = 0; d < 32; ++d) a += s_wv[d] * wo[(h * 32 + d) * HIDS + tid];
    wvo_t[(size_t)tid * 2048 + hc] = f2bf(a);
}

// ---------- prep: transpose f32 [R][C] -> bf16 [C][R] ----------
__global__ __launch_bounds__(256) void k_transp(const float* __restrict__ in,
        unsigned short* __restrict__ out, int R, int C) {
    __shared__ float s[32][36];
    int tid = threadIdx.x;
    int ct = blockIdx.x * 32, rt = blockIdx.y * 32;
    int r = tid >> 3, c4 = (tid & 7) * 4;
    float4 f = *(const float4*)&in[(size_t)(rt + r) * C + ct + c4];
    s[r][c4] = f.x; s[r][c4 + 1] = f.y; s[r][c4 + 2] = f.z; s[r][c4 + 3] = f.w;
    __syncthreads();
    int ro = tid >> 3, k4 = (tid & 7) * 4;
    ushort4 o;
    o.x = f2bf(s[k4][ro]);     o.y = f2bf(s[k4 + 1][ro]);
    o.z = f2bf(s[k4 + 2][ro]); o.w = f2bf(s[k4 + 3][ro]);
    *(ushort4*)&out[(size_t)(ct + ro) * R + rt + k4] = o;
}

// ---------- attention: 4 tokens/block, MFMA scores, VALU mix -> xmix bf16 ----------
__global__ __launch_bounds__(256) void k_attn(
        const float* __restrict__ x, const unsigned short* __restrict__ qkbT,
        const float* __restrict__ qb, unsigned short* __restrict__ xmix) {
    __shared__ __align__(16) unsigned short sX[92 * 256];
    __shared__ float s_at[4][NVS][NHS];
    int tid = threadIdx.x;
    int wave = tid >> 6, lane = tid & 63;
    int m = lane & 15, g = lane >> 4;
    size_t t0 = (size_t)blockIdx.x * 4;

    short8 qf[8];
    #pragma unroll
    for (int kk = 0; kk < 8; ++kk)
        qf[kk] = *(const short8*)&qkbT[m * HIDS + kk * 32 + g * 8];

    const float* xg = x + t0 * (NVS * HIDS);
    #pragma unroll
    for (int i = 0; i < 10; ++i) {
        int s = i * 256 + tid;
        int row = s >> 5, cc = s & 31;
        float4 f0 = *(const float4*)(xg + s * 8);
        float4 f1 = *(const float4*)(xg + s * 8 + 4);
        uint4 pk;
        pk.x = pk2(f0.x, f0.y); pk.y = pk2(f0.z, f0.w);
        pk.z = pk2(f1.x, f1.y); pk.w = pk2(f1.z, f1.w);
        int c = cc ^ (row & 7);
        *(uint4*)&sX[row * 256 + c * 8] = pk;
    }
    __syncthreads();

    int rbase = wave * NVS;
    floatx4 sc0 = {0.f, 0.f, 0.f, 0.f}, sc1 = {0.f, 0.f, 0.f, 0.f};
    #pragma unroll
    for (int kk = 0; kk < 8; ++kk) {
        int r0 = rbase + m;
        int c0 = (kk * 4 + g) ^ (r0 & 7);
        short8 a0 = *(const short8*)&sX[r0 * 256 + c0 * 8];
        int r1 = rbase + 16 + m;
        int c1 = (kk * 4 + g) ^ (r1 & 7);
        short8 a1 = *(const short8*)&sX[r1 * 256 + c1 * 8];
        sc0 = __builtin_amdgcn_mfma_f32_16x16x32_bf16(a0, qf[kk], sc0, 0, 0, 0);
        sc1 = __builtin_amdgcn_mfma_f32_16x16x32_bf16(a1, qf[kk], sc1, 0, 0, 0);
    }
    if (m < NHS) {
        #pragma unroll
        for (int r = 0; r < 4; ++r) s_at[wave][g * 4 + r][m] = sc0[r];
        if (g == 0) {
            #pragma unroll
            for (int r = 0; r < 4; ++r) s_at[wave][16 + r][m] = sc1[r];
        }
    }
    __syncthreads();

    if (lane < NHS) {
        float qbh = qb[lane];
        float sv[NVS]; float mx = -1e30f;
        #pragma unroll
        for (int v = 0; v < NVS; ++v) {
            float sc = (s_at[wave][v][lane] + qbh) * 0.17677669529663687f;
            sv[v] = sc; mx = fmaxf(mx, sc);
        }
        float sum = 0.f;
        #pragma unroll
        for (int v = 0; v < NVS; ++v) { sv[v] = expf(sv[v] - mx); sum += sv[v]; }
        float inv = 1.f / sum;
        #pragma unroll
        for (int v = 0; v < NVS; ++v) s_at[wave][v][lane] = sv[v] * inv;
    }
    __syncthreads();

    floatx4 acc[NHS];
    #pragma unroll
    for (int h = 0; h < NHS; ++h) acc[h] = (floatx4){0.f, 0.f, 0.f, 0.f};
    #pragma unroll
    for (int v = 0; v < NVS; ++v) {
        int r = rbase + v;
        int cidx = (((lane >> 1) ^ (r & 7)) << 3) + ((lane & 1) << 2);
        uint2 u = *(const uint2*)&sX[r * 256 + cidx];
        float x0 = bf2f(u.x & 0xffffu), x1 = bf2f(u.x >> 16);
        float x2 = bf2f(u.y & 0xffffu), x3 = bf2f(u.y >> 16);
        float4 w0 = *(const float4*)&s_at[wave][v][0];
        float4 w1 = *(const float4*)&s_at[wave][v][4];
        float wv8[8] = {w0.x, w0.y, w0.z, w0.w, w1.x, w1.y, w1.z, w1.w};
        #pragma unroll
        for (int h = 0; h < NHS; ++h) {
            acc[h][0] += wv8[h] * x0; acc[h][1] += wv8[h] * x1;
            acc[h][2] += wv8[h] * x2; acc[h][3] += wv8[h] * x3;
        }
    }
    unsigned short* op = xmix + (t0 + wave) * 2048;
    #pragma unroll
    for (int h = 0; h < NHS; ++h) {
        uint2 o; o.x = pk2(acc[h][0], acc[h][1]); o.y = pk2(acc[h][2], acc[h][3]);
        *(uint2*)&op[h * 256 + lane * 4] = o;
    }
}

// ---------- MFMA GEMM: out = act(A[M,K]bf16 @ Bt[N,K]bf16^T + bias) ----------
template <int K, int N, int BN, bool GELU, bool OUT_BF16>
__global__ __launch_bounds__(256) void k_mgemm(
        const unsigned short* __restrict__ A,
        const unsigned short* __restrict__ Bt,
        const float* __restrict__ bias, void* __restrict__ outp) {
    constexpr int BM = 128, BK = 64;
    constexpr int NJ = BN / 32;
    __shared__ __align__(16) unsigned short sA[BM * BK];
    __shared__ __align__(16) unsigned short sB[BN * BK];
    int tid = threadIdx.x;
    int wave = tid >> 6, lane = tid & 63;
    int m = lane & 15, g = lane >> 4;
    int wm = (wave & 1) * 64, wn = (wave >> 1) * (BN / 2);
    size_t t0 = (size_t)blockIdx.x * BM;
    int n0 = blockIdx.y * BN;

    floatx4 acc[4][NJ];
    #pragma unroll
    for (int i = 0; i < 4; ++i)
        #pragma unroll
        for (int j = 0; j < NJ; ++j) acc[i][j] = (floatx4){0.f, 0.f, 0.f, 0.f};

    for (int k0 = 0; k0 < K; k0 += BK) {
        __syncthreads();
        #pragma unroll
        for (int i = 0; i < 4; ++i) {
            int s = i * 256 + tid;
            int row = s >> 3, cc = s & 7;
            int gc = cc ^ (row & 7);
            gload16(A + (t0 + row) * K + k0 + gc * 8, (char*)sA + s * 16);
        }
        #pragma unroll
        for (int i = 0; i < BN / 32; ++i) {
            int s = i * 256 + tid;
            int row = s >> 3, cc = s & 7;
            int gc = cc ^ (row & 7);
            gload16(Bt + (size_t)(n0 + row) * K + k0 + gc * 8, (char*)sB + s * 16);
        }
        __syncthreads();
        #pragma unroll
        for (int kk = 0; kk < 2; ++kk) {
            short8 af[4]; short8 bfr[NJ];
            #pragma unroll
            for (int i = 0; i < 4; ++i) {
                int row = wm + i * 16 + m;
                int c = (kk * 4 + g) ^ (row & 7);
                af[i] = *(const short8*)&sA[row * BK + c * 8];
            }
            #pragma unroll
            for (int j = 0; j < NJ; ++j) {
                int row = wn + j * 16 + m;
                int c = (kk * 4 + g) ^ (row & 7);
                bfr[j] = *(const short8*)&sB[row * BK + c * 8];
            }
            #pragma unroll
            for (int i = 0; i < 4; ++i)
                #pragma unroll
                for (int j = 0; j < NJ; ++j)
                    acc[i][j] = __builtin_amdgcn_mfma_f32_16x16x32_bf16(af[i], bfr[j], acc[i][j], 0, 0, 0);
        }
    }
    float bj[NJ];
    #pragma unroll
    for (int j = 0; j < NJ; ++j) bj[j] = bias[n0 + wn + j * 16 + m];
    #pragma unroll
    for (int i = 0; i < 4; ++i) {
        #pragma unroll
        for (int r = 0; r < 4; ++r) {
            size_t grow = t0 + wm + i * 16 + g * 4 + r;
            #pragma unroll
            for (int j = 0; j < NJ; ++j) {
                float v = acc[i][j][r] + bj[j];
                if (GELU) v = 0.5f * v * (1.f + erff(v * 0.70710678118654752f));
                if (OUT_BF16) {
                    float v2 = __shfl_xor(v, 1);
                    if (!(lane & 1)) {
                        *(unsigned int*)((unsigned short*)outp + grow * N + n0 + wn + j * 16 + m) = pk2(v, v2);
                    }
                } else {
                    ((float*)outp)[grow * N + n0 + wn + j * 16 + m] = v;
                }
            }
        }
    }
}

// ---------- LayerNorm (f32 in, f32 or bf16 out) ----------
template <bool OUT_BF16>
__global__ __launch_bounds__(256) void k_ln(
        const float* __restrict__ in, const float* __restrict__ g,
        const float* __restrict__ b, void* __restrict__ outp) {
    int tid = threadIdx.x;
    size_t t = (size_t)blockIdx.x * 4 + (tid >> 6);
    int l = tid & 63;
    float4 v = ((const float4*)(in + t * HIDS))[l];
    float s = v.x + v.y + v.z + v.w;
    float sq = v.x * v.x + v.y * v.y + v.z * v.z + v.w * v.w;
    #pragma unroll
    for (int mm = 1; mm < 64; mm <<= 1) {
        s += __shfl_xor(s, mm, 64);
        sq += __shfl_xor(sq, mm, 64);
    }
    float mean = s * (1.f / HIDS);
    float var = sq * (1.f / HIDS) - mean * mean;
    float rstd = rsqrtf(var + 1e-5f);
    float4 g4 = ((const float4*)g)[l];
    float4 b4 = ((const float4*)b)[l];
    float ox = (v.x - mean) * rstd * g4.x + b4.x;
    float oy = (v.y - mean) * rstd * g4.y + b4.y;
    float oz = (v.z - mean) * rstd * g4.z + b4.z;
    float ow = (v.w - mean) * rstd * g4.w + b4.w;
    if (OUT_BF16) {
        uint2 o; o.x = pk2(ox, oy); o.y = pk2(oz, ow);
        *(uint2*)((unsigned short*)outp + t * HIDS + l * 4) = o;
    } else {
        float4 o; o.x = ox; o.y = oy; o.z = oz; o.w = ow;
        ((float4*)((float*)outp + t * HIDS))[l] = o;
    }
}

// ---------- fused LN2 + selection logits + softmax -> weights ----------
__global__ __launch_bounds__(256) void k_wsoft(
        const float* __restrict__ in, const float* __restrict__ lng,
        const float* __restrict__ lnb, const float* __restrict__ ww,
        const float* __restrict__ bw, float* __restrict__ wout) {
    __shared__ float s_p[16][HIDS + 1];
    __shared__ float s_red[2][16][16];
    __shared__ float s_ms[16][2];
    __shared__ float s_lg[16][NVS];
    int tid = threadIdx.x;
    size_t t0 = (size_t)blockIdx.x * 16;
    #pragma unroll
    for (int i = 0; i < 4; ++i) {
        int idx4 = i * 256 + tid;
        float4 f = ((const float4*)(in + t0 * HIDS))[idx4];
        int flat = idx4 * 4;
        int r = flat >> 8, c = flat & 255;
        s_p[r][c] = f.x; s_p[r][c + 1] = f.y; s_p[r][c + 2] = f.z; s_p[r][c + 3] = f.w;
    }
    __syncthreads();
    int r = tid >> 4, jg = tid & 15;
    float sum = 0.f, sq = 0.f;
    #pragma unroll
    for (int i = 0; i < 16; ++i) {
        float a = s_p[r][jg * 16 + i]; sum += a; sq += a * a;
    }
    s_red[0][r][jg] = sum; s_red[1][r][jg] = sq;
    __syncthreads();
    if (jg == 0) {
        float ts = 0.f, tq = 0.f;
        #pragma unroll
        for (int i = 0; i < 16; ++i) { ts += s_red[0][r][i]; tq += s_red[1][r][i]; }
        float mean = ts * (1.f / HIDS);
        float var = tq * (1.f / HIDS) - mean * mean;
        s_ms[r][0] = mean; s_ms[r][1] = rsqrtf(var + 1e-5f);
    }
    __syncthreads();
    float mean = s_ms[r][0], rstd = s_ms[r][1];
    #pragma unroll
    for (int i = 0; i < 16; ++i) {
        int c = jg * 16 + i;
        s_p[r][c] = (s_p[r][c] - mean) * rstd * lng[c] + lnb[c];
    }
    __syncthreads();
    if (jg < 10) {
        int o = jg * 2;
        float a0 = bw[o], a1 = bw[o + 1];
        #pragma unroll 4
        for (int c = 0; c < HIDS; ++c) {
            float a = s_p[r][c];
            const float2 w = *(const float2*)(ww + c * NVS + o);
            a0 += a * w.x; a1 += a * w.y;
        }
        s_lg[r][o] = a0; s_lg[r][o + 1] = a1;
    }
    __syncthreads();
    if (tid < 16) {
        int rr = tid;
        float mx = -1e30f;
        #pragma unroll
        for (int v = 0; v < NVS; ++v) mx = fmaxf(mx, s_lg[rr][v]);
        float e[NVS]; float ssum = 0.f;
        #pragma unroll
        for (int v = 0; v < NVS; ++v) { e[v] = expf(s_lg[rr][v] - mx); ssum += e[v]; }
        float inv = 1.f / ssum;
        #pragma unroll
        for (int v = 0; v < NVS; ++v) wout[(t0 + rr) * NVS + v] = e[v] * inv;
    }
}

// ---------- vs_output = weights . x ----------
__global__ __launch_bounds__(256) void k_vsout(
        const float* __restrict__ x, const float* __restrict__ wts,
        float* __restrict__ outp) {
    int tid = threadIdx.x;
    size_t t = (size_t)blockIdx.x * 4 + (tid >> 6);
    int l = tid & 63;
    const float4* xt = (const float4*)(x + t * (NVS * HIDS));
    const float* wr = wts + t * NVS;
    float4 acc = make_float4(0.f, 0.f, 0.f, 0.f);
    #pragma unroll
    for (int v = 0; v < NVS; ++v) {
        float w = wr[v];
        float4 a = xt[v * 64 + l];
        acc.x += w * a.x; acc.y += w * a.y; acc.z += w * a.z; acc.w += w * a.w;
    }
    ((float4*)(outp + t * HIDS))[l] = acc;
}

extern "C" void kernel_launch(void* const* d_in, const int* in_sizes, int n_in,
                              void* d_out, int out_size, void* d_ws, size_t ws_size,
                              hipStream_t stream) {
    const float* x     = (const float*)d_in[0];
    const float* cls   = (const float*)d_in[1];
    const float* wq    = (const float*)d_in[2];
    const float* bq    = (const float*)d_in[3];
    const float* wk    = (const float*)d_in[4];
    const float* bk    = (const float*)d_in[5];
    const float* wv    = (const float*)d_in[6];
    const float* bv    = (const float*)d_in[7];
    const float* wo    = (const float*)d_in[8];
    const float* bo    = (const float*)d_in[9];
    const float* ln1_g = (const float*)d_in[10];
    const float* ln1_b = (const float*)d_in[11];
    const float* w1    = (const float*)d_in[12];
    const float* b1    = (const float*)d_in[13];
    const float* w2    = (const float*)d_in[14];
    const float* b2    = (const float*)d_in[15];
    const float* ln2_g = (const float*)d_in[16];
    const float* ln2_b = (const float*)d_in[17];
    const float* ww    = (const float*)d_in[18];
    const float* bw    = (const float*)d_in[19];

    float* outf   = (float*)d_out;
    float* vs_out = outf;
    float* w_out  = outf + (size_t)BT * HIDS;

    char* ws = (char*)d_ws;
    unsigned short* qkbT = (unsigned short*)ws;                    // 8 KB
    float* qb   = (float*)(ws + 8192);                             // 32 B
    float* bvo  = (float*)(ws + 8448);                             // 1 KB
    unsigned short* w1t   = (unsigned short*)(ws + 16384);         // 512 KB
    unsigned short* w2t   = (unsigned short*)(ws + 16384 + 524288);        // 512 KB
    unsigned short* wvo_t = (unsigned short*)(ws + 16384 + 1048576);       // 1 MB
    char* big = ws + 16384 + 1048576 + 1048576;
    unsigned short* bufA = (unsigned short*)big;                   // 67.1 MB (xmix, then h1)
    float* buf1 = (float*)(big + (size_t)BT * 2048 * 2);           // 16.8 MB
    unsigned short* hb = (unsigned short*)(big + (size_t)BT * 2048 * 2 + (size_t)BT * HIDS * 4); // 8.4 MB

    // prep (runs every call; weights restored by harness each launch)
    k_fold<<<1, 256, 0, stream>>>(cls, wq, bq, wk, bk, qkbT, qb);
    k_bvo<<<1, 256, 0, stream>>>(bv, wo, bo, bvo);
    k_wvo<<<2048, 256, 0, stream>>>(wv, wo, wvo_t);
    k_transp<<<dim3(32, 8), 256, 0, stream>>>(w1, w1t, 256, 1024);
    k_transp<<<dim3(8, 32), 256, 0, stream>>>(w2, w2t, 1024, 256);

    // main pipeline
    k_attn<<<BT / 4, 256, 0, stream>>>(x, qkbT, qb, bufA);
    k_mgemm<2048, 256, 64, false, false><<<dim3(128, 4), 256, 0, stream>>>(bufA, wvo_t, bvo, buf1);
    k_ln<true><<<BT / 4, 256, 0, stream>>>(buf1, ln1_g, ln1_b, hb);
    k_mgemm<256, 1024, 128, true, true><<<dim3(128, 8), 256, 0, stream>>>(hb, w1t, b1, bufA);
    k_mgemm<1024, 256, 64, false, false><<<dim3(128, 4), 256, 0, stream>>>(bufA, w2t, b2, buf1);
    k_wsoft<<<BT / 16, 256, 0, stream>>>(buf1, ln2_g, ln2_b, ww, bw, w_out);
    k_vsout<<<BT / 4, 256, 0, stream>>>(x, w_out, vs_out);
}